// Round 17
// baseline (66.042 us; speedup 1.0000x reference)
//
#include <hip/hip_runtime.h>

// Window_Crop: per-batch sliding-window average pooling over 5 aspect ratios
// (stride 1) + argmax over first 4 ratio groups.
//
// Ratios (exact Python float semantics: 1024 // 25.6 == 39.0):
//   (32,32) N=6561  off 0
//   (25,39) N=6512  off 6561
//   (39,25) N=6512  off 13073
//   (38,26) N=6525  off 19585
//   (26,38) N=6525  off 26110   (excluded from argmax)
//   total 32635
//
// Base = R14 (best, 38.96us): 512 blocks x 2 images, 51KB LDS -> 2 blocks/CU,
// T14 prefetch of image B, stride-1 scalar window stores, LDS-only barriers
// (s_waitcnt lgkmcnt(0); s_barrier -- global stores stay in flight).
// R17 = R16 retry: NONTEMPORAL stores for the 134 MB score stream (never
// re-read; normal stores write-allocate into L2 and churn it) + nontemporal
// loads for the once-read input. (R16 compile fix: NT builtins reject
// HIP_vector_type -- use clang ext_vector float4 for the NT loads.)

#define B_TOTAL 1024
#define GRID    512
#define HW      112
#define NPIX    (HW * HW)
#define NV4     (NPIX / 4)           // 3136 float4 per image
#define PITCH   113
#define TOTAL_W 32635
#define BLOCK   512
#define LDV4    7                    // ceil(3136 / 512)
#define SEG     28                   // 112 / 4 segments per scan line

typedef float vfloat4 __attribute__((ext_vector_type(4)));  // NT-builtin-legal

// LDS-only barrier: waits LDS/shfl ops, NOT the global store queue.
#define BAR() asm volatile("s_waitcnt lgkmcnt(0)\n\ts_barrier" ::: "memory")

template<int KH, int KW, int OFF, bool TRACK>
__device__ __forceinline__ void windows_group(const float* __restrict__ S,
                                              float* __restrict__ out_scores,
                                              int tid, float& bestv, int& besti) {
    constexpr int OH = HW - KH + 1;
    constexpr int OW = HW - KW + 1;
    constexpr int N  = OH * OW;
    constexpr int D  = KH * PITCH;        // bottom-row offset (dwords)
    constexpr float inv = 1.0f / (float)(KH * KW);
    for (int w = tid; w < N; w += BLOCK) {
        const int i  = w / OW;            // const divisor -> magic mul
        const int j  = w - i * OW;
        const int A  = i * PITCH + j;     // top-left corner
        const int Ab = A + D;             // bottom-left corner
        const float s = S[Ab + KW] - S[A + KW] - S[Ab] + S[A];
        const float sc = s * inv;
        __builtin_nontemporal_store(sc, &out_scores[OFF + w]);  // nt: no L2 alloc
        if (TRACK && sc > bestv) { bestv = sc; besti = OFF + w; }
    }
}

__device__ __forceinline__ void scans(float* __restrict__ S, int tid, int bl) {
    // row-wise prefix sums: 112 rows x 4 segments of 28; partials in regs,
    // shfl fixup. 113-stride across threads: conflict-free.
    if (tid < HW * 4) {
        const int r = tid >> 2, s = tid & 3;
        float* row = &S[(r + 1) * PITCH];
        const int c0 = 1 + s * SEG;
        float pref[SEG];
        float run = 0.0f;
        #pragma unroll
        for (int k = 0; k < SEG; ++k) { run += row[c0 + k]; pref[k] = run; }
        const float v0 = __shfl(run, bl, 64), v1 = __shfl(run, bl + 1, 64),
                    v2 = __shfl(run, bl + 2, 64);
        float off = 0.0f;
        if (s > 0) off += v0;
        if (s > 1) off += v1;
        if (s > 2) off += v2;
        #pragma unroll
        for (int k = 0; k < SEG; ++k) row[c0 + k] = pref[k] + off;
    }
    BAR();
    // column-wise prefix sums, same scheme (consecutive addrs across threads)
    if (tid < HW * 4) {
        const int c = tid >> 2, s = tid & 3;
        float* col = &S[c + 1];
        const int r0 = 1 + s * SEG;
        float pref[SEG];
        float run = 0.0f;
        #pragma unroll
        for (int k = 0; k < SEG; ++k) { run += col[(r0 + k) * PITCH]; pref[k] = run; }
        const float v0 = __shfl(run, bl, 64), v1 = __shfl(run, bl + 1, 64),
                    v2 = __shfl(run, bl + 2, 64);
        float off = 0.0f;
        if (s > 0) off += v0;
        if (s > 1) off += v1;
        if (s > 2) off += v2;
        #pragma unroll
        for (int k = 0; k < SEG; ++k) col[(r0 + k) * PITCH] = pref[k] + off;
    }
    BAR();
}

__device__ __forceinline__ void write_img(float* __restrict__ S, const vfloat4* v,
                                          int tid) {
    #pragma unroll
    for (int k = 0; k < LDV4; ++k) {
        const int i = tid + k * BLOCK;
        if (i < NV4) {
            const int r = i / (HW / 4);
            const int c = (i - r * (HW / 4)) * 4;
            float* dst = &S[(r + 1) * PITCH + (c + 1)];
            dst[0] = v[k].x; dst[1] = v[k].y; dst[2] = v[k].z; dst[3] = v[k].w;
        }
    }
}

__device__ __forceinline__ void windows_phase(const float* __restrict__ S,
                                              float* __restrict__ out, int b,
                                              int tid, int lane,
                                              float* wv, int* wi) {
    float bestv = -3.402823466e+38f;
    int   besti = 0;
    float* out_scores = out + 2 * B_TOTAL + (size_t)b * TOTAL_W;

    windows_group<32, 32,     0, true >(S, out_scores, tid, bestv, besti);
    windows_group<25, 39,  6561, true >(S, out_scores, tid, bestv, besti);
    windows_group<39, 25, 13073, true >(S, out_scores, tid, bestv, besti);
    windows_group<38, 26, 19585, true >(S, out_scores, tid, bestv, besti);
    windows_group<26, 38, 26110, false>(S, out_scores, tid, bestv, besti);

    #pragma unroll
    for (int d = 32; d > 0; d >>= 1) {
        const float ov = __shfl_down(bestv, d, 64);
        const int   oi = __shfl_down(besti, d, 64);
        if (ov > bestv || (ov == bestv && oi < besti)) { bestv = ov; besti = oi; }
    }
    if (lane == 0) { wv[tid >> 6] = bestv; wi[tid >> 6] = besti; }
    BAR();
    if (tid == 0) {
        float bv = wv[0]; int bi = wi[0];
        #pragma unroll
        for (int k = 1; k < BLOCK / 64; ++k) {
            if (wv[k] > bv || (wv[k] == bv && wi[k] < bi)) { bv = wv[k]; bi = wi[k]; }
        }
        out[b]           = (float)bi;    // idx (exact in fp32: < 2^24)
        out[B_TOTAL + b] = bv;           // prop_scores
    }
}

__global__ __launch_bounds__(BLOCK)
void window_crop_kernel(const float* __restrict__ x, float* __restrict__ out) {
    __shared__ float S[PITCH * PITCH];           // 51,076 B integral image
    __shared__ float wv[BLOCK / 64];
    __shared__ int   wi[BLOCK / 64];

    const int tid  = threadIdx.x;
    const int lane = tid & 63;
    const int bl   = lane & ~3;

    const int bA = blockIdx.x;
    const int bB = blockIdx.x + GRID;

    // zero border row/col once; images only touch [1..112]^2
    for (int i = tid; i < PITCH; i += BLOCK) {
        S[i] = 0.0f;
        S[i * PITCH] = 0.0f;
    }

    // ---- image A: load -> LDS -> scans ----
    vfloat4 va[LDV4];
    const vfloat4* imgA = (const vfloat4*)(x + (size_t)bA * NPIX);
    #pragma unroll
    for (int k = 0; k < LDV4; ++k) {
        const int i = tid + k * BLOCK;
        if (i < NV4) va[k] = __builtin_nontemporal_load(&imgA[i]);
    }
    write_img(S, va, tid);
    BAR();
    scans(S, tid, bl);

    // ---- issue image B's loads (consumed after A's window phase) ----
    vfloat4 vb[LDV4];
    const vfloat4* imgB = (const vfloat4*)(x + (size_t)bB * NPIX);
    #pragma unroll
    for (int k = 0; k < LDV4; ++k) {
        const int i = tid + k * BLOCK;
        if (i < NV4) vb[k] = __builtin_nontemporal_load(&imgB[i]);
    }

    // ---- image A: windows + argmax (write-heavy; B loads in flight) ----
    windows_phase(S, out, bA, tid, lane, wv, wi);
    BAR();                           // all window LDS reads of S done

    // ---- image B: LDS -> scans -> windows ----
    write_img(S, vb, tid);
    BAR();
    scans(S, tid, bl);
    windows_phase(S, out, bB, tid, lane, wv, wi);
}

extern "C" void kernel_launch(void* const* d_in, const int* in_sizes, int n_in,
                              void* d_out, int out_size, void* d_ws, size_t ws_size,
                              hipStream_t stream) {
    const float* x = (const float*)d_in[0];
    float* out     = (float*)d_out;
    window_crop_kernel<<<GRID, BLOCK, 0, stream>>>(x, out);
}

// Round 18
// 51.574 us; speedup vs baseline: 1.2805x; 1.2805x over previous
//
#include <hip/hip_runtime.h>

// Window_Crop: per-batch sliding-window average pooling over 5 aspect ratios
// (stride 1) + argmax over first 4 ratio groups.
//
// Ratios (exact Python float semantics: 1024 // 25.6 == 39.0):
//   g0 (32,32) off 0      OH81 OW81    g1 (25,39) off 6561  OH88 OW74
//   g2 (39,25) off 13073  OH74 OW88    g3 (38,26) off 19585 OH75 OW87
//   g4 (26,38) off 26110  OH87 OW75 (excluded from argmax)   total 32635
//
// Base = R14 (best, 38.96us): 512 blocks x 2 images, 51KB LDS -> 2 blocks/CU,
// T14 prefetch of image B, LDS-only barriers (stores stay in flight).
// R18 change: FLOAT4 SCORE STORES, clean version (R11's was confounded: its
// pack layout put fast+slow paths in ~96% of waves). Pack grid lives on the
// absolute 16B-aligned address grid; each task = (row, pack) -> 4 windows in
// ONE row (no re-divide anywhere). Full packs (~90%): one global_store_
// dwordx4. Edge packs: predicated scalar stores. Mechanism under test:
// per-wave vmcnt queue is ~63 slots; 4B/slot caps bytes-in-flight (the
// 7 TB/s fill kernel uses 16B/slot). NT removed everywhere (R17: regression).

#define B_TOTAL 1024
#define GRID    512
#define HW      112
#define NPIX    (HW * HW)
#define NV4     (NPIX / 4)           // 3136 float4 per image
#define PITCH   113
#define ISZ     (PITCH * PITCH)      // 12769 floats
#define TOTAL_W 32635
#define BLOCK   512
#define LDV4    7                    // ceil(3136 / 512)
#define SEG     28                   // 112 / 4 segments per scan line

// LDS-only barrier: waits LDS/shfl ops, NOT the global store queue.
#define BAR() asm volatile("s_waitcnt lgkmcnt(0)\n\ts_barrier" ::: "memory")

template<int KH, int KW, int OFF, bool TRACK>
__device__ __forceinline__ void windows_group(const float* __restrict__ S,
                                              float* __restrict__ gout,
                                              int tid, float& bestv, int& besti) {
    constexpr int OH  = HW - KH + 1;
    constexpr int OW  = HW - KW + 1;
    constexpr int NPK = (OW + 6) >> 2;    // packs per row = ceil((OW+3)/4)
    constexpr int NT  = OH * NPK;
    constexpr int D   = KH * PITCH;
    constexpr float inv = 1.0f / (float)(KH * KW);
    for (int t = tid; t < NT; t += BLOCK) {
        const int i = t / NPK;            // const divisor -> magic mul (1/pack)
        const int q = t - i * NPK;
        float* const rowp = gout + OFF + i * OW;          // row output base
        const int mis = (int)(((size_t)rowp >> 2) & 3);   // dwords to 16B grid
        const int j0  = 4 * q - mis;                      // first window col
        if (j0 >= OW) continue;                           // pack past row end
        const int A = i * PITCH + j0;     // S is +4-padded: A >= -3 is safe
        float4 r;
        r.x = (S[A + D + KW]     - S[A + KW]     - S[A + D]     + S[A])     * inv;
        r.y = (S[A + D + KW + 1] - S[A + KW + 1] - S[A + D + 1] + S[A + 1]) * inv;
        r.z = (S[A + D + KW + 2] - S[A + KW + 2] - S[A + D + 2] + S[A + 2]) * inv;
        r.w = (S[A + D + KW + 3] - S[A + KW + 3] - S[A + D + 3] + S[A + 3]) * inv;
        if (j0 >= 0 && j0 + 4 <= OW) {
            *(float4*)(rowp + j0) = r;    // 16B-aligned global_store_dwordx4
        } else {
            if ((unsigned)(j0 + 0) < (unsigned)OW) rowp[j0 + 0] = r.x;
            if ((unsigned)(j0 + 1) < (unsigned)OW) rowp[j0 + 1] = r.y;
            if ((unsigned)(j0 + 2) < (unsigned)OW) rowp[j0 + 2] = r.z;
            if ((unsigned)(j0 + 3) < (unsigned)OW) rowp[j0 + 3] = r.w;
        }
        if (TRACK) {                      // index-explicit tie-break + mask
            const int w = OFF + i * OW + j0;
            if ((unsigned)(j0 + 0) < (unsigned)OW &&
                (r.x > bestv || (r.x == bestv && w + 0 < besti))) { bestv = r.x; besti = w + 0; }
            if ((unsigned)(j0 + 1) < (unsigned)OW &&
                (r.y > bestv || (r.y == bestv && w + 1 < besti))) { bestv = r.y; besti = w + 1; }
            if ((unsigned)(j0 + 2) < (unsigned)OW &&
                (r.z > bestv || (r.z == bestv && w + 2 < besti))) { bestv = r.z; besti = w + 2; }
            if ((unsigned)(j0 + 3) < (unsigned)OW &&
                (r.w > bestv || (r.w == bestv && w + 3 < besti))) { bestv = r.w; besti = w + 3; }
        }
    }
}

__device__ __forceinline__ void scans(float* __restrict__ S, int tid, int bl) {
    // row-wise prefix sums: 112 rows x 4 segments of 28; partials in regs,
    // shfl fixup. 113-stride across threads: conflict-free.
    if (tid < HW * 4) {
        const int r = tid >> 2, s = tid & 3;
        float* row = &S[(r + 1) * PITCH];
        const int c0 = 1 + s * SEG;
        float pref[SEG];
        float run = 0.0f;
        #pragma unroll
        for (int k = 0; k < SEG; ++k) { run += row[c0 + k]; pref[k] = run; }
        const float v0 = __shfl(run, bl, 64), v1 = __shfl(run, bl + 1, 64),
                    v2 = __shfl(run, bl + 2, 64);
        float off = 0.0f;
        if (s > 0) off += v0;
        if (s > 1) off += v1;
        if (s > 2) off += v2;
        #pragma unroll
        for (int k = 0; k < SEG; ++k) row[c0 + k] = pref[k] + off;
    }
    BAR();
    // column-wise prefix sums, same scheme (consecutive addrs across threads)
    if (tid < HW * 4) {
        const int c = tid >> 2, s = tid & 3;
        float* col = &S[c + 1];
        const int r0 = 1 + s * SEG;
        float pref[SEG];
        float run = 0.0f;
        #pragma unroll
        for (int k = 0; k < SEG; ++k) { run += col[(r0 + k) * PITCH]; pref[k] = run; }
        const float v0 = __shfl(run, bl, 64), v1 = __shfl(run, bl + 1, 64),
                    v2 = __shfl(run, bl + 2, 64);
        float off = 0.0f;
        if (s > 0) off += v0;
        if (s > 1) off += v1;
        if (s > 2) off += v2;
        #pragma unroll
        for (int k = 0; k < SEG; ++k) col[(r0 + k) * PITCH] = pref[k] + off;
    }
    BAR();
}

__device__ __forceinline__ void write_img(float* __restrict__ S, const float4* v,
                                          int tid) {
    #pragma unroll
    for (int k = 0; k < LDV4; ++k) {
        const int i = tid + k * BLOCK;
        if (i < NV4) {
            const int r = i / (HW / 4);
            const int c = (i - r * (HW / 4)) * 4;
            float* dst = &S[(r + 1) * PITCH + (c + 1)];
            dst[0] = v[k].x; dst[1] = v[k].y; dst[2] = v[k].z; dst[3] = v[k].w;
        }
    }
}

__device__ __forceinline__ void windows_phase(const float* __restrict__ S,
                                              float* __restrict__ out, int b,
                                              int tid, int lane,
                                              float* wv, int* wi) {
    float bestv = -3.402823466e+38f;
    int   besti = 0;
    float* gout = out + 2 * B_TOTAL + (size_t)b * TOTAL_W;

    windows_group<32, 32,     0, true >(S, gout, tid, bestv, besti);
    windows_group<25, 39,  6561, true >(S, gout, tid, bestv, besti);
    windows_group<39, 25, 13073, true >(S, gout, tid, bestv, besti);
    windows_group<38, 26, 19585, true >(S, gout, tid, bestv, besti);
    windows_group<26, 38, 26110, false>(S, gout, tid, bestv, besti);

    #pragma unroll
    for (int d = 32; d > 0; d >>= 1) {
        const float ov = __shfl_down(bestv, d, 64);
        const int   oi = __shfl_down(besti, d, 64);
        if (ov > bestv || (ov == bestv && oi < besti)) { bestv = ov; besti = oi; }
    }
    if (lane == 0) { wv[tid >> 6] = bestv; wi[tid >> 6] = besti; }
    BAR();
    if (tid == 0) {
        float bv = wv[0]; int bi = wi[0];
        #pragma unroll
        for (int k = 1; k < BLOCK / 64; ++k) {
            if (wv[k] > bv || (wv[k] == bv && wi[k] < bi)) { bv = wv[k]; bi = wi[k]; }
        }
        out[b]           = (float)bi;    // idx (exact in fp32: < 2^24)
        out[B_TOTAL + b] = bv;           // prop_scores
    }
}

__global__ __launch_bounds__(BLOCK)
void window_crop_kernel(const float* __restrict__ x, float* __restrict__ out) {
    __shared__ __align__(16) float S_raw[ISZ + 8];   // +-4 pad for edge packs
    __shared__ float wv[BLOCK / 64];
    __shared__ int   wi[BLOCK / 64];
    float* const S = S_raw + 4;

    const int tid  = threadIdx.x;
    const int lane = tid & 63;
    const int bl   = lane & ~3;

    const int bA = blockIdx.x;
    const int bB = blockIdx.x + GRID;

    // zero border row/col once; images only touch [1..112]^2
    for (int i = tid; i < PITCH; i += BLOCK) {
        S[i] = 0.0f;
        S[i * PITCH] = 0.0f;
    }

    // ---- image A: load -> LDS -> scans ----
    float4 va[LDV4];
    const float4* imgA = (const float4*)(x + (size_t)bA * NPIX);
    #pragma unroll
    for (int k = 0; k < LDV4; ++k) {
        const int i = tid + k * BLOCK;
        if (i < NV4) va[k] = imgA[i];
    }
    write_img(S, va, tid);
    BAR();
    scans(S, tid, bl);

    // ---- issue image B's loads (consumed after A's window phase) ----
    float4 vb[LDV4];
    const float4* imgB = (const float4*)(x + (size_t)bB * NPIX);
    #pragma unroll
    for (int k = 0; k < LDV4; ++k) {
        const int i = tid + k * BLOCK;
        if (i < NV4) vb[k] = imgB[i];
    }

    // ---- image A: windows + argmax (write-heavy; B loads in flight) ----
    windows_phase(S, out, bA, tid, lane, wv, wi);
    BAR();                           // all window LDS reads of S done

    // ---- image B: LDS -> scans -> windows ----
    write_img(S, vb, tid);
    BAR();
    scans(S, tid, bl);
    windows_phase(S, out, bB, tid, lane, wv, wi);
}

extern "C" void kernel_launch(void* const* d_in, const int* in_sizes, int n_in,
                              void* d_out, int out_size, void* d_ws, size_t ws_size,
                              hipStream_t stream) {
    const float* x = (const float*)d_in[0];
    float* out     = (float*)d_out;
    window_crop_kernel<<<GRID, BLOCK, 0, stream>>>(x, out);
}

// Round 19
// 51.502 us; speedup vs baseline: 1.2823x; 1.0014x over previous
//
#include <hip/hip_runtime.h>

// Window_Crop: per-batch sliding-window average pooling over 5 aspect ratios
// (stride 1) + argmax over first 4 ratio groups.
//
// Ratios (exact Python float semantics: 1024 // 25.6 == 39.0):
//   g0 (32,32) off 0      OH81 OW81    g1 (25,39) off 6561  OH88 OW74
//   g2 (39,25) off 13073  OH74 OW88    g3 (38,26) off 19585 OH75 OW87
//   g4 (26,38) off 26110  OH87 OW75 (excluded from argmax)   total 32635
//
// Base = R14 (best, 38.96us): 512 blocks x 2 images, 51KB LDS -> 2 blocks/CU,
// T14 prefetch of image B, LDS-only barriers (stores stay in flight).
// R18 change: FLOAT4 SCORE STORES, clean version (R11's was confounded: its
// pack layout put fast+slow paths in ~96% of waves). Pack grid lives on the
// absolute 16B-aligned address grid; each task = (row, pack) -> 4 windows in
// ONE row (no re-divide anywhere). Full packs (~90%): one global_store_
// dwordx4. Edge packs: predicated scalar stores. Mechanism under test:
// per-wave vmcnt queue is ~63 slots; 4B/slot caps bytes-in-flight (the
// 7 TB/s fill kernel uses 16B/slot). NT removed everywhere (R17: regression).

#define B_TOTAL 1024
#define GRID    512
#define HW      112
#define NPIX    (HW * HW)
#define NV4     (NPIX / 4)           // 3136 float4 per image
#define PITCH   113
#define ISZ     (PITCH * PITCH)      // 12769 floats
#define TOTAL_W 32635
#define BLOCK   512
#define LDV4    7                    // ceil(3136 / 512)
#define SEG     28                   // 112 / 4 segments per scan line

// LDS-only barrier: waits LDS/shfl ops, NOT the global store queue.
#define BAR() asm volatile("s_waitcnt lgkmcnt(0)\n\ts_barrier" ::: "memory")

template<int KH, int KW, int OFF, bool TRACK>
__device__ __forceinline__ void windows_group(const float* __restrict__ S,
                                              float* __restrict__ gout,
                                              int tid, float& bestv, int& besti) {
    constexpr int OH  = HW - KH + 1;
    constexpr int OW  = HW - KW + 1;
    constexpr int NPK = (OW + 6) >> 2;    // packs per row = ceil((OW+3)/4)
    constexpr int NT  = OH * NPK;
    constexpr int D   = KH * PITCH;
    constexpr float inv = 1.0f / (float)(KH * KW);
    for (int t = tid; t < NT; t += BLOCK) {
        const int i = t / NPK;            // const divisor -> magic mul (1/pack)
        const int q = t - i * NPK;
        float* const rowp = gout + OFF + i * OW;          // row output base
        const int mis = (int)(((size_t)rowp >> 2) & 3);   // dwords to 16B grid
        const int j0  = 4 * q - mis;                      // first window col
        if (j0 >= OW) continue;                           // pack past row end
        const int A = i * PITCH + j0;     // S is +4-padded: A >= -3 is safe
        float4 r;
        r.x = (S[A + D + KW]     - S[A + KW]     - S[A + D]     + S[A])     * inv;
        r.y = (S[A + D + KW + 1] - S[A + KW + 1] - S[A + D + 1] + S[A + 1]) * inv;
        r.z = (S[A + D + KW + 2] - S[A + KW + 2] - S[A + D + 2] + S[A + 2]) * inv;
        r.w = (S[A + D + KW + 3] - S[A + KW + 3] - S[A + D + 3] + S[A + 3]) * inv;
        if (j0 >= 0 && j0 + 4 <= OW) {
            *(float4*)(rowp + j0) = r;    // 16B-aligned global_store_dwordx4
        } else {
            if ((unsigned)(j0 + 0) < (unsigned)OW) rowp[j0 + 0] = r.x;
            if ((unsigned)(j0 + 1) < (unsigned)OW) rowp[j0 + 1] = r.y;
            if ((unsigned)(j0 + 2) < (unsigned)OW) rowp[j0 + 2] = r.z;
            if ((unsigned)(j0 + 3) < (unsigned)OW) rowp[j0 + 3] = r.w;
        }
        if (TRACK) {                      // index-explicit tie-break + mask
            const int w = OFF + i * OW + j0;
            if ((unsigned)(j0 + 0) < (unsigned)OW &&
                (r.x > bestv || (r.x == bestv && w + 0 < besti))) { bestv = r.x; besti = w + 0; }
            if ((unsigned)(j0 + 1) < (unsigned)OW &&
                (r.y > bestv || (r.y == bestv && w + 1 < besti))) { bestv = r.y; besti = w + 1; }
            if ((unsigned)(j0 + 2) < (unsigned)OW &&
                (r.z > bestv || (r.z == bestv && w + 2 < besti))) { bestv = r.z; besti = w + 2; }
            if ((unsigned)(j0 + 3) < (unsigned)OW &&
                (r.w > bestv || (r.w == bestv && w + 3 < besti))) { bestv = r.w; besti = w + 3; }
        }
    }
}

__device__ __forceinline__ void scans(float* __restrict__ S, int tid, int bl) {
    // row-wise prefix sums: 112 rows x 4 segments of 28; partials in regs,
    // shfl fixup. 113-stride across threads: conflict-free.
    if (tid < HW * 4) {
        const int r = tid >> 2, s = tid & 3;
        float* row = &S[(r + 1) * PITCH];
        const int c0 = 1 + s * SEG;
        float pref[SEG];
        float run = 0.0f;
        #pragma unroll
        for (int k = 0; k < SEG; ++k) { run += row[c0 + k]; pref[k] = run; }
        const float v0 = __shfl(run, bl, 64), v1 = __shfl(run, bl + 1, 64),
                    v2 = __shfl(run, bl + 2, 64);
        float off = 0.0f;
        if (s > 0) off += v0;
        if (s > 1) off += v1;
        if (s > 2) off += v2;
        #pragma unroll
        for (int k = 0; k < SEG; ++k) row[c0 + k] = pref[k] + off;
    }
    BAR();
    // column-wise prefix sums, same scheme (consecutive addrs across threads)
    if (tid < HW * 4) {
        const int c = tid >> 2, s = tid & 3;
        float* col = &S[c + 1];
        const int r0 = 1 + s * SEG;
        float pref[SEG];
        float run = 0.0f;
        #pragma unroll
        for (int k = 0; k < SEG; ++k) { run += col[(r0 + k) * PITCH]; pref[k] = run; }
        const float v0 = __shfl(run, bl, 64), v1 = __shfl(run, bl + 1, 64),
                    v2 = __shfl(run, bl + 2, 64);
        float off = 0.0f;
        if (s > 0) off += v0;
        if (s > 1) off += v1;
        if (s > 2) off += v2;
        #pragma unroll
        for (int k = 0; k < SEG; ++k) col[(r0 + k) * PITCH] = pref[k] + off;
    }
    BAR();
}

__device__ __forceinline__ void write_img(float* __restrict__ S, const float4* v,
                                          int tid) {
    #pragma unroll
    for (int k = 0; k < LDV4; ++k) {
        const int i = tid + k * BLOCK;
        if (i < NV4) {
            const int r = i / (HW / 4);
            const int c = (i - r * (HW / 4)) * 4;
            float* dst = &S[(r + 1) * PITCH + (c + 1)];
            dst[0] = v[k].x; dst[1] = v[k].y; dst[2] = v[k].z; dst[3] = v[k].w;
        }
    }
}

__device__ __forceinline__ void windows_phase(const float* __restrict__ S,
                                              float* __restrict__ out, int b,
                                              int tid, int lane,
                                              float* wv, int* wi) {
    float bestv = -3.402823466e+38f;
    int   besti = 0;
    float* gout = out + 2 * B_TOTAL + (size_t)b * TOTAL_W;

    windows_group<32, 32,     0, true >(S, gout, tid, bestv, besti);
    windows_group<25, 39,  6561, true >(S, gout, tid, bestv, besti);
    windows_group<39, 25, 13073, true >(S, gout, tid, bestv, besti);
    windows_group<38, 26, 19585, true >(S, gout, tid, bestv, besti);
    windows_group<26, 38, 26110, false>(S, gout, tid, bestv, besti);

    #pragma unroll
    for (int d = 32; d > 0; d >>= 1) {
        const float ov = __shfl_down(bestv, d, 64);
        const int   oi = __shfl_down(besti, d, 64);
        if (ov > bestv || (ov == bestv && oi < besti)) { bestv = ov; besti = oi; }
    }
    if (lane == 0) { wv[tid >> 6] = bestv; wi[tid >> 6] = besti; }
    BAR();
    if (tid == 0) {
        float bv = wv[0]; int bi = wi[0];
        #pragma unroll
        for (int k = 1; k < BLOCK / 64; ++k) {
            if (wv[k] > bv || (wv[k] == bv && wi[k] < bi)) { bv = wv[k]; bi = wi[k]; }
        }
        out[b]           = (float)bi;    // idx (exact in fp32: < 2^24)
        out[B_TOTAL + b] = bv;           // prop_scores
    }
}

__global__ __launch_bounds__(BLOCK)
void window_crop_kernel(const float* __restrict__ x, float* __restrict__ out) {
    __shared__ __align__(16) float S_raw[ISZ + 8];   // +-4 pad for edge packs
    __shared__ float wv[BLOCK / 64];
    __shared__ int   wi[BLOCK / 64];
    float* const S = S_raw + 4;

    const int tid  = threadIdx.x;
    const int lane = tid & 63;
    const int bl   = lane & ~3;

    const int bA = blockIdx.x;
    const int bB = blockIdx.x + GRID;

    // zero border row/col once; images only touch [1..112]^2
    for (int i = tid; i < PITCH; i += BLOCK) {
        S[i] = 0.0f;
        S[i * PITCH] = 0.0f;
    }

    // ---- image A: load -> LDS -> scans ----
    float4 va[LDV4];
    const float4* imgA = (const float4*)(x + (size_t)bA * NPIX);
    #pragma unroll
    for (int k = 0; k < LDV4; ++k) {
        const int i = tid + k * BLOCK;
        if (i < NV4) va[k] = imgA[i];
    }
    write_img(S, va, tid);
    BAR();
    scans(S, tid, bl);

    // ---- issue image B's loads (consumed after A's window phase) ----
    float4 vb[LDV4];
    const float4* imgB = (const float4*)(x + (size_t)bB * NPIX);
    #pragma unroll
    for (int k = 0; k < LDV4; ++k) {
        const int i = tid + k * BLOCK;
        if (i < NV4) vb[k] = imgB[i];
    }

    // ---- image A: windows + argmax (write-heavy; B loads in flight) ----
    windows_phase(S, out, bA, tid, lane, wv, wi);
    BAR();                           // all window LDS reads of S done

    // ---- image B: LDS -> scans -> windows ----
    write_img(S, vb, tid);
    BAR();
    scans(S, tid, bl);
    windows_phase(S, out, bB, tid, lane, wv, wi);
}

extern "C" void kernel_launch(void* const* d_in, const int* in_sizes, int n_in,
                              void* d_out, int out_size, void* d_ws, size_t ws_size,
                              hipStream_t stream) {
    const float* x = (const float*)d_in[0];
    float* out     = (float*)d_out;
    window_crop_kernel<<<GRID, BLOCK, 0, stream>>>(x, out);
}